// Round 1
// baseline (92.816 us; speedup 1.0000x reference)
//
#include <hip/hip_runtime.h>
#include <math.h>

#define NBUCK 4096
#define CAP   4096
#define KMAX  1000

// ---- ws layout (32-bit word offsets) ----
#define HIST_W  0
#define META_W  (NBUCK)             // meta[0]=T bucket, meta[1]=candidate count
#define CANDK_W (NBUCK + 16)        // u64[CAP] keys (byte off 16448, 8-aligned)
#define SS_W    (CANDK_W + 2*CAP)   // sigmoid scores [1024]
#define Y1_W    (SS_W + 1024)
#define X1_W    (Y1_W + 1024)
#define Y2_W    (X1_W + 1024)
#define X2_W    (Y2_W + 1024)
#define AR_W    (X2_W + 1024)
#define RF_W    (AR_W + 1024)       // 32 words: row-has-suppression flags
#define MASK_W  (RF_W + 32)         // 1000 rows x 32 words suppression bitmask

// orderable bucket for v >= 1.0f (top 16 bits of positive float are monotone)
__device__ __forceinline__ unsigned bucket_of(float v) {
    unsigned b = (__float_as_uint(v) >> 16) - 0x3F80u;
    return b > (NBUCK - 1u) ? (NBUCK - 1u) : b;
}

// replicate f32 sigmoid 1/(1+expf(-x)) with correctly-rounded expf
__device__ __forceinline__ float sigmoid_ref(float x) {
    x = fminf(fmaxf(x, -100.0f), 100.0f);
    float ef = (float)exp(-(double)x);
    return 1.0f / (1.0f + ef);
}

__global__ void __launch_bounds__(256) k_hist(const float* __restrict__ sc, int n,
                                              unsigned* __restrict__ hist) {
    __shared__ unsigned h[NBUCK];
    for (int i = threadIdx.x; i < NBUCK; i += 256) h[i] = 0u;
    __syncthreads();
    int gt = blockIdx.x * 256 + threadIdx.x;
    int stride = gridDim.x * 256;
    int n4 = n >> 2;
    const float4* s4 = (const float4*)sc;
    for (int i = gt; i < n4; i += stride) {
        float4 v = s4[i];
        if (v.x >= 1.0f) atomicAdd(&h[bucket_of(v.x)], 1u);
        if (v.y >= 1.0f) atomicAdd(&h[bucket_of(v.y)], 1u);
        if (v.z >= 1.0f) atomicAdd(&h[bucket_of(v.z)], 1u);
        if (v.w >= 1.0f) atomicAdd(&h[bucket_of(v.w)], 1u);
    }
    for (int i = (n4 << 2) + gt; i < n; i += stride) {
        float v = sc[i];
        if (v >= 1.0f) atomicAdd(&h[bucket_of(v)], 1u);
    }
    __syncthreads();
    for (int i = threadIdx.x; i < NBUCK; i += 256) {
        unsigned cv = h[i];
        if (cv) atomicAdd(&hist[i], cv);
    }
}

__global__ void __launch_bounds__(256) k_thresh(const unsigned* __restrict__ hist,
                                                unsigned* __restrict__ meta) {
    __shared__ unsigned c[256];
    int t = threadIdx.x;
    unsigned s = 0;
#pragma unroll
    for (int k = 0; k < 16; k++) s += hist[t * 16 + k];
    c[t] = s;
    __syncthreads();
    // inclusive suffix scan (Hillis-Steele)
    for (int off = 1; off < 256; off <<= 1) {
        unsigned v = (t + off < 256) ? c[t + off] : 0u;
        __syncthreads();
        c[t] += v;
        __syncthreads();
    }
    unsigned total = c[0];
    unsigned Ktar = total < KMAX ? total : KMAX;
    if (Ktar == 0u) { if (t == 0) meta[0] = 0u; return; }
    unsigned ssn = (t < 255) ? c[t + 1] : 0u;
    if (c[t] >= Ktar && ssn < Ktar) {   // exactly one thread: boundary chunk
        unsigned acc = ssn;
        int T = t * 16;
        for (int b = t * 16 + 15; b >= t * 16; b--) {
            acc += hist[b];
            if (acc >= Ktar) { T = b; break; }
        }
        meta[0] = (unsigned)T;
    }
}

__device__ __forceinline__ void try_emit(float v, int idx, unsigned T,
                                         unsigned* meta, unsigned long long* candk) {
    if (v >= 1.0f && bucket_of(v) >= T) {
        unsigned p = atomicAdd(&meta[1], 1u);
        if (p < CAP) {
            float s = sigmoid_ref(v);
            candk[p] = ((unsigned long long)__float_as_uint(s) << 32)
                     | (unsigned long long)(0xFFFFFFFFu - (unsigned)idx);
        }
    }
}

__global__ void __launch_bounds__(256) k_compact(const float* __restrict__ sc, int n,
                                                 unsigned* __restrict__ meta,
                                                 unsigned long long* __restrict__ candk) {
    unsigned T = meta[0];
    int gt = blockIdx.x * 256 + threadIdx.x;
    int stride = gridDim.x * 256;
    int n4 = n >> 2;
    const float4* s4 = (const float4*)sc;
    for (int i = gt; i < n4; i += stride) {
        float4 v = s4[i];
        int b = i << 2;
        try_emit(v.x, b + 0, T, meta, candk);
        try_emit(v.y, b + 1, T, meta, candk);
        try_emit(v.z, b + 2, T, meta, candk);
        try_emit(v.w, b + 3, T, meta, candk);
    }
    for (int i = (n4 << 2) + gt; i < n; i += stride)
        try_emit(sc[i], i, T, meta, candk);
}

__global__ void __launch_bounds__(256) k_rank(const unsigned long long* __restrict__ candk,
                                              const unsigned* __restrict__ meta,
                                              const float4* __restrict__ rb4,
                                              const float4* __restrict__ an4,
                                              float* __restrict__ ss,
                                              float* __restrict__ y1a, float* __restrict__ x1a,
                                              float* __restrict__ y2a, float* __restrict__ x2a,
                                              float* __restrict__ ara) {
    __shared__ unsigned long long kl[CAP];
    int C = (int)meta[1]; if (C > CAP) C = CAP;
    int K = C < KMAX ? C : KMAX;
    for (int i = threadIdx.x; i < C; i += 256) kl[i] = candk[i];
    __syncthreads();
    int j = blockIdx.x * 256 + threadIdx.x;
    if (j >= C) return;
    unsigned long long kj = kl[j];
    int rank = 0;
    for (int k = 0; k < C; k++) rank += (kl[k] > kj) ? 1 : 0;
    if (rank >= K) return;
    unsigned idx = 0xFFFFFFFFu - (unsigned)kj;
    float s = __uint_as_float((unsigned)(kj >> 32));
    float4 rb = rb4[idx];
    float4 an = an4[idx];
    const float inv = 0.0078125f;  // 1/128, exact
    float xc = rb.x * inv * an.z + an.x;
    float yc = rb.y * inv * an.w + an.y;
    float w  = rb.z * inv * an.z;
    float h  = rb.w * inv * an.w;
    float ya = yc - h * 0.5f, yb = yc + h * 0.5f;
    float xa = xc - w * 0.5f, xb = xc + w * 0.5f;
    float y1 = fminf(ya, yb), y2 = fmaxf(ya, yb);
    float x1 = fminf(xa, xb), x2 = fmaxf(xa, xb);
    ss[rank] = s;
    y1a[rank] = y1; x1a[rank] = x1; y2a[rank] = y2; x2a[rank] = x2;
    ara[rank] = (y2 - y1) * (x2 - x1);
}

__global__ void __launch_bounds__(256) k_mask(const unsigned* __restrict__ meta,
                                              const float* __restrict__ y1a, const float* __restrict__ x1a,
                                              const float* __restrict__ y2a, const float* __restrict__ x2a,
                                              const float* __restrict__ ara,
                                              unsigned* __restrict__ mask, unsigned* __restrict__ rf) {
    int C = (int)meta[1]; if (C > CAP) C = CAP;
    int K = C < KMAX ? C : KMAX;
    int gt = blockIdx.x * 256 + threadIdx.x;
    int i = gt >> 5, w = gt & 31;
    if (i >= K) return;
    float y1 = y1a[i], x1 = x1a[i], y2 = y2a[i], x2 = x2a[i], ai = ara[i];
    unsigned bits = 0u;
    int jb = w << 5;
    for (int jj = 0; jj < 32; jj++) {
        int j = jb + jj;
        if (j > i && j < K) {
            float iy = fmaxf(0.0f, fminf(y2, y2a[j]) - fmaxf(y1, y1a[j]));
            float ix = fmaxf(0.0f, fminf(x2, x2a[j]) - fmaxf(x1, x1a[j]));
            float inter = iy * ix;
            float iou = inter / (ai + ara[j] - inter);
            if (iou > 0.3f) bits |= (1u << jj);
        }
    }
    mask[i * 32 + w] = bits;
    if (bits) atomicOr(&rf[i >> 5], 1u << (i & 31));
}

extern __shared__ unsigned dyn_lds[];  // 1000*32 u32 mask copy

__global__ void __launch_bounds__(1024) k_nms(const unsigned* __restrict__ meta,
                                              const unsigned* __restrict__ mask,
                                              const unsigned* __restrict__ rf,
                                              const float* __restrict__ ss,
                                              const float* __restrict__ y1a, const float* __restrict__ x1a,
                                              const float* __restrict__ y2a, const float* __restrict__ x2a,
                                              const float* __restrict__ scale, const float* __restrict__ pad_y,
                                              const float* __restrict__ pad_x,
                                              float* __restrict__ out) {
    __shared__ unsigned keep_lds[32];
    __shared__ unsigned psum[1024];
    int C = (int)meta[1]; if (C > CAP) C = CAP;
    int K = C < KMAX ? C : KMAX;
    int t = threadIdx.x;
    for (int i = t; i < 32 * K; i += 1024) dyn_lds[i] = mask[i];
    __syncthreads();

    // serial greedy-NMS bit scan on wave 0 (lane l<32 owns keep word l)
    if (t < 64) {
        int l = t;
        unsigned keepw = 0xFFFFFFFFu;
        unsigned rfw = (l < 32) ? rf[l] : 0u;
        unsigned arw = keepw & rfw;   // rows still kept that have suppressions
        int nw = (K + 31) >> 5;
        for (int w = 0; w < nw; w++) {
            unsigned done = 0u;
            unsigned aw = __shfl(arw, w) & ~done;
            while (aw) {
                int b = __ffs((int)aw) - 1;
                int i = (w << 5) + b;
                unsigned m = (l < 32) ? dyn_lds[i * 32 + l] : 0u;
                keepw &= ~m;
                arw = keepw & rfw;
                done |= (b == 31) ? 0xFFFFFFFFu : ((1u << (b + 1)) - 1u);
                aw = __shfl(arw, w) & ~done;
            }
        }
        if (l < 32) keep_lds[l] = keepw;
    }
    __syncthreads();

    // valid + stable compaction + denorm output
    int i = t;
    int valid = 0;
    float sv = 0.0f;
    if (i < K) {
        unsigned kb = (keep_lds[i >> 5] >> (i & 31)) & 1u;
        sv = ss[i];
        valid = (kb && sv >= 0.75f) ? 1 : 0;
    }
    psum[t] = (unsigned)valid;
    __syncthreads();
    for (int off = 1; off < 1024; off <<= 1) {
        unsigned v = (t >= off) ? psum[t - off] : 0u;
        __syncthreads();
        psum[t] += v;
        __syncthreads();
    }
    int nvalid = (int)psum[1023];
    float s = scale[0];
    float py = pad_y[0], px = pad_x[0];
    if (i < K && valid) {
        int p = (int)psum[t] - 1;
        out[p * 5 + 0] = (y1a[i] * s) * 256.0f - py;
        out[p * 5 + 1] = (x1a[i] * s) * 256.0f - px;
        out[p * 5 + 2] = (y2a[i] * s) * 256.0f - py;
        out[p * 5 + 3] = (x2a[i] * s) * 256.0f - px;
        out[p * 5 + 4] = sv;
    }
    for (int r = t; r < KMAX; r += 1024) {
        if (r >= nvalid) {
            out[r * 5 + 0] = 0.0f; out[r * 5 + 1] = 0.0f; out[r * 5 + 2] = 0.0f;
            out[r * 5 + 3] = 0.0f; out[r * 5 + 4] = 0.0f;
        }
    }
}

extern "C" void kernel_launch(void* const* d_in, const int* in_sizes, int n_in,
                              void* d_out, int out_size, void* d_ws, size_t ws_size,
                              hipStream_t stream) {
    const float* raw_boxes  = (const float*)d_in[0];
    const float* raw_scores = (const float*)d_in[1];
    const float* anchors    = (const float*)d_in[2];
    const float* scale      = (const float*)d_in[3];
    const float* pad_y      = (const float*)d_in[4];
    const float* pad_x      = (const float*)d_in[5];
    float* out = (float*)d_out;
    int n = in_sizes[1];

    unsigned* wsu = (unsigned*)d_ws;
    float*    wsf = (float*)d_ws;
    unsigned* hist = wsu + HIST_W;
    unsigned* meta = wsu + META_W;
    unsigned long long* candk = (unsigned long long*)(wsu + CANDK_W);
    float* ss  = wsf + SS_W;
    float* y1a = wsf + Y1_W; float* x1a = wsf + X1_W;
    float* y2a = wsf + Y2_W; float* x2a = wsf + X2_W;
    float* ara = wsf + AR_W;
    unsigned* rf   = wsu + RF_W;
    unsigned* mask = wsu + MASK_W;

    // zero hist + meta, and rf flags
    hipMemsetAsync(wsu, 0, (size_t)(CANDK_W) * 4, stream);
    hipMemsetAsync(rf, 0, 32 * 4, stream);

    k_hist<<<512, 256, 0, stream>>>(raw_scores, n, hist);
    k_thresh<<<1, 256, 0, stream>>>(hist, meta);
    k_compact<<<512, 256, 0, stream>>>(raw_scores, n, meta, candk);
    k_rank<<<CAP / 256, 256, 0, stream>>>(candk, meta, (const float4*)raw_boxes,
                                          (const float4*)anchors, ss, y1a, x1a, y2a, x2a, ara);
    k_mask<<<(KMAX * 32 + 255) / 256, 256, 0, stream>>>(meta, y1a, x1a, y2a, x2a, ara, mask, rf);
    hipFuncSetAttribute((const void*)k_nms, hipFuncAttributeMaxDynamicSharedMemorySize, 32 * KMAX * 4);
    k_nms<<<1, 1024, 32 * KMAX * 4, stream>>>(meta, mask, rf, ss, y1a, x1a, y2a, x2a,
                                              scale, pad_y, pad_x, out);
}